// Round 4
// baseline (163.637 us; speedup 1.0000x reference)
//
#include <hip/hip_runtime.h>
#include <hip/hip_bf16.h>

// MC3DAD kNN(k=5) covariance-trace curvature. B=8, N=4096, f32.
// Round 4: single fused kernel.
//  - Query-per-lane, candidates in REGISTERS broadcast via v_readlane ->
//    SGPR operands (zero memory ops in the scan inner loop).
//  - 8 waves/block each scan a 512-candidate segment for the block's 64
//    queries; cross-wave threshold sharing via LDS atomicMin on float bits
//    (stale reads are conservative -> no barriers).
//  - Keep/drain machinery is round-3's proven superset logic (absmax 0.0):
//    fast fma filter with +6e-5 inflated lagged tau, always-write LDS
//    append, exact numpy-tree recompute + strict-< stable push5 in
//    ascending index order, final ranking by packed (sqrt-dist, idx) u64.
//  - Curvature fused via last-block fan-in per batch (trace lives in d_out,
//    device-scope atomic counter in ws, threadfence release/acquire);
//    reduction tree is bit-identical to round-3's curvature_kernel.

typedef unsigned long long ull;
typedef unsigned short u16;
typedef unsigned int u32;

constexpr int N_PTS  = 4096;
constexpr int BATCH  = 8;
constexpr int KNN    = 5;
constexpr int NTHR   = 512;            // 8 waves
constexpr int WPB    = 8;              // waves per block
constexpr int QPB    = 64;             // queries per block (1 per lane)
constexpr int SEGLEN = 512;            // candidates per wave
constexpr int CHUNKS = 8;              // 64-candidate chunks per wave
constexpr int KSLOT  = 16;             // per-thread append slots
constexpr int TRIG   = 12;             // drain if cnt > TRIG after a 4-group

__device__ __forceinline__ float rl(float v, int j) {
    return __int_as_float(__builtin_amdgcn_readlane(__float_as_int(v), j));
}
__device__ __forceinline__ ull umin64(ull a, ull b) { return a < b ? a : b; }
__device__ __forceinline__ ull umax64(ull a, ull b) { return a < b ? b : a; }

// Branchless stable insert of (dd,idx) into ascending 5-list (strict <).
__device__ __forceinline__ void push5(float dd, int idx,
                                      float d[KNN], int ix[KNN])
{
    float ad = dd; int ai = idx;
    #pragma unroll
    for (int p = 0; p < KNN - 1; ++p) {
        const bool lt = ad < d[p];
        const float md = lt ? ad : d[p];
        const int   mi = lt ? ai : ix[p];
        const float xd = lt ? d[p] : ad;
        const int   xi = lt ? ix[p] : ai;
        d[p] = md; ix[p] = mi; ad = xd; ai = xi;
    }
    const bool lt = ad < d[KNN - 1];
    d[KNN - 1]  = lt ? ad : d[KNN - 1];
    ix[KNN - 1] = lt ? ai : ix[KNN - 1];
}

// Merge two ascending sorted 5-lists (u64 lex keys) -> ascending top-5.
__device__ __forceinline__ void merge5(ull a[KNN], const ull* __restrict__ b)
{
    const ull r0 = umin64(a[0], b[0]);
    const ull r1 = umin64(umin64(a[1], b[1]), umax64(a[0], b[0]));
    const ull r2 = umin64(umin64(a[2], b[2]),
                          umin64(umax64(a[1], b[0]), umax64(a[0], b[1])));
    const ull r3 = umin64(umin64(a[3], b[3]),
                   umin64(umax64(a[2], b[0]),
                   umin64(umax64(a[1], b[1]), umax64(a[0], b[2]))));
    const ull r4 = umin64(umin64(a[4], b[4]),
                   umin64(umin64(umax64(a[3], b[0]), umax64(a[2], b[1])),
                          umin64(umax64(a[1], b[2]), umax64(a[0], b[3]))));
    a[0] = r0; a[1] = r1; a[2] = r2; a[3] = r3; a[4] = r4;
}

struct Sh {
    u16 buf[KSLOT * NTHR];            // 16 KB append buffer
    u32 tau_bits[QPB];                // shared 5th-best d2 bits per query
    int lastflag;
    union {
        ull   mrg[QPB][WPB][KNN];     // 20 KB wave top-5 lists
        float red[256];               // fan-in reduction scratch
    } u;
};

__device__ __forceinline__ void drain_buf(int& cnt, float qx, float qy, float qz, float qw,
                                          float dq[KNN], int iq[KNN], float& tau,
                                          const float* __restrict__ batch,
                                          const u16* lanebuf, u32* tau_bits, int lane)
{
    for (int j = 0; __any(j < cnt); ++j) {
        if (j < cnt) {
            const int idx = lanebuf[(size_t)j * NTHR];
            const float x = batch[idx * 3 + 0];
            const float y = batch[idx * 3 + 1];
            const float z = batch[idx * 3 + 2];
            // exact numpy trees (round-3 verbatim)
            const float sq  = __fadd_rn(__fadd_rn(__fmul_rn(x, x), __fmul_rn(y, y)),
                                        __fmul_rn(z, z));
            const float dot = __fadd_rn(__fadd_rn(__fmul_rn(qx, x), __fmul_rn(qy, y)),
                                        __fmul_rn(qz, z));
            const float dd  = __fsub_rn(__fadd_rn(qw, sq), __fmul_rn(2.0f, dot));
            push5(dd, idx, dq, iq);
        }
    }
    cnt = 0;
    atomicMin(&tau_bits[lane], __float_as_uint(dq[KNN - 1]));   // d2 >= 0: bits monotone
    const u32 tb = *(volatile u32*)&tau_bits[lane];             // stale-safe re-read
    tau = __uint_as_float(tb) - qw + 6e-5f;                     // inf stays inf
}

__global__ __launch_bounds__(NTHR, 4)
void fused_kernel(const float* __restrict__ pcd, float* __restrict__ out,
                  u32* __restrict__ ctr)
{
    __shared__ Sh sh;

    const int b    = blockIdx.y;
    const int qb   = blockIdx.x;
    const int t    = threadIdx.x;
    const int lane = t & 63;
    const int wave = t >> 6;
    const float* __restrict__ batch = pcd + (size_t)b * N_PTS * 3;

    if (t < QPB) sh.tau_bits[t] = 0x7f800000u;   // +inf

    // ---- query per lane (exact |q|^2 tree) ----
    const int q = qb * QPB + lane;
    const float qx = batch[q * 3 + 0];
    const float qy = batch[q * 3 + 1];
    const float qz = batch[q * 3 + 2];
    const float qw = __fadd_rn(__fadd_rn(__fmul_rn(qx, qx), __fmul_rn(qy, qy)),
                               __fmul_rn(qz, qz));

    // ---- wave's candidate segment into registers ----
    const int wbase = wave * SEGLEN;
    float cx[CHUNKS], cy[CHUNKS], cz[CHUNKS], cw[CHUNKS];
    #pragma unroll
    for (int c = 0; c < CHUNKS; ++c) {
        const int idx = wbase + c * 64 + lane;
        cx[c] = batch[idx * 3 + 0];
        cy[c] = batch[idx * 3 + 1];
        cz[c] = batch[idx * 3 + 2];
        cw[c] = __fadd_rn(__fadd_rn(__fmul_rn(cx[c], cx[c]), __fmul_rn(cy[c], cy[c])),
                          __fmul_rn(cz[c], cz[c]));
    }
    __syncthreads();   // tau_bits initialized

    float dq[KNN]; int iq[KNN];
    #pragma unroll
    for (int r = 0; r < KNN; ++r) { dq[r] = __builtin_inff(); iq[r] = 0x7fffffff; }

    u16* lanebuf = sh.buf + t;
    int   cnt = 0;
    float tau = __builtin_inff();

    // ---- scan: readlane-broadcast candidate vs 64 per-lane queries ----
    for (int c = 0; c < CHUNKS; ++c) {
        const u32 tb = *(volatile u32*)&sh.tau_bits[lane];    // cross-wave tighten
        tau = __uint_as_float(tb) - qw + 6e-5f;
        const int cbase = wbase + c * 64;
        for (int j0 = 0; j0 < 64; j0 += 4) {
            #pragma unroll
            for (int v = 0; v < 4; ++v) {
                const int j = j0 + v;
                const float sx = rl(cx[c], j);
                const float sy = rl(cy[c], j);
                const float sz = rl(cz[c], j);
                const float sw = rl(cw[c], j);
                const float dot = fmaf(qx, sx, fmaf(qy, sy, qz * sz));
                const float t2  = fmaf(-2.0f, dot, sw);
                const bool keep = t2 < tau;
                if (__any(keep)) {
                    lanebuf[(size_t)cnt * NTHR] = (u16)(cbase + j);  // always-write
                    cnt += keep ? 1 : 0;
                }
            }
            if (__any(cnt > TRIG))
                drain_buf(cnt, qx, qy, qz, qw, dq, iq, tau, batch,
                          lanebuf, sh.tau_bits, lane);
        }
    }
    drain_buf(cnt, qx, qy, qz, qw, dq, iq, tau, batch, lanebuf, sh.tau_bits, lane);

    // ---- pack (sqrt-dist, idx) keys, full lex sort (round-2/3 proven) ----
    ull key[KNN];
    #pragma unroll
    for (int r = 0; r < KNN; ++r) {
        const float dist = __fsqrt_rn(fmaxf(dq[r], 0.0f));
        key[r] = ((ull)__float_as_uint(dist) << 32) | (unsigned)iq[r];
    }
    #pragma unroll
    for (int i = 0; i < KNN - 1; ++i)
        #pragma unroll
        for (int p = 0; p < KNN - 1 - i; ++p) {
            const ull lo = umin64(key[p], key[p + 1]);
            const ull hi = umax64(key[p], key[p + 1]);
            key[p] = lo; key[p + 1] = hi;
        }
    #pragma unroll
    for (int r = 0; r < KNN; ++r) sh.u.mrg[lane][wave][r] = key[r];
    __syncthreads();

    // ---- wave 0: merge 8 wave-lists, covariance trace, store raw trace ----
    if (wave == 0) {
        ull cur[KNN];
        #pragma unroll
        for (int r = 0; r < KNN; ++r) cur[r] = sh.u.mrg[lane][0][r];
        #pragma unroll
        for (int w = 1; w < WPB; ++w) merge5(cur, &sh.u.mrg[lane][w][0]);

        float nx[KNN], ny[KNN], nz[KNN];
        #pragma unroll
        for (int r = 0; r < KNN; ++r) {
            const int sel = (int)(cur[r] & 0xffffffffull);
            nx[r] = batch[sel * 3 + 0];
            ny[r] = batch[sel * 3 + 1];
            nz[r] = batch[sel * 3 + 2];
        }
        float sx = nx[0], sy = ny[0], sz = nz[0];
        #pragma unroll
        for (int r = 1; r < KNN; ++r) {
            sx = __fadd_rn(sx, nx[r]);
            sy = __fadd_rn(sy, ny[r]);
            sz = __fadd_rn(sz, nz[r]);
        }
        const float ccx = __fdiv_rn(sx, 5.0f);
        const float ccy = __fdiv_rn(sy, 5.0f);
        const float ccz = __fdiv_rn(sz, 5.0f);

        float sxx = 0.0f, syy = 0.0f, szz = 0.0f;
        #pragma unroll
        for (int r = 0; r < KNN; ++r) {
            const float dx = __fsub_rn(nx[r], ccx);
            const float dy = __fsub_rn(ny[r], ccy);
            const float dz = __fsub_rn(nz[r], ccz);
            sxx = __fadd_rn(sxx, __fmul_rn(dx, dx));
            syy = __fadd_rn(syy, __fmul_rn(dy, dy));
            szz = __fadd_rn(szz, __fmul_rn(dz, dz));
        }
        const float trace = __fadd_rn(__fadd_rn(__fmul_rn(sxx, 0.25f),
                                                __fmul_rn(syy, 0.25f)),
                                      __fmul_rn(szz, 0.25f));
        out[(size_t)b * N_PTS + qb * QPB + lane] = trace;
    }

    // ---- fan-in: last block of this batch normalizes the whole batch ----
    __syncthreads();
    if (t == 0) {
        __threadfence();                                   // release traces
        const u32 old = atomicAdd(&ctr[b], 1u);
        sh.lastflag = (old == (u32)(gridDim.x - 1)) ? 1 : 0;
    }
    __syncthreads();
    if (sh.lastflag) {
        __threadfence();                                   // acquire traces
        float* __restrict__ ob = out + (size_t)b * N_PTS;
        if (t < 256) {
            float s = 0.0f;
            #pragma unroll
            for (int i = 0; i < 16; ++i) s += ob[t + i * 256];   // round-3 order
            sh.u.red[t] = s;
        }
        __syncthreads();
        for (int o = 128; o > 0; o >>= 1) {
            if (t < o) sh.u.red[t] += sh.u.red[t + o];
            __syncthreads();
        }
        const float denom = sh.u.red[0] + 1e-8f;
        #pragma unroll
        for (int i = 0; i < 8; ++i) {
            const int x = t + i * NTHR;
            ob[x] = ob[x] / denom;                          // same IEEE div as r3
        }
    }
}

extern "C" void kernel_launch(void* const* d_in, const int* in_sizes, int n_in,
                              void* d_out, int out_size, void* d_ws, size_t ws_size,
                              hipStream_t stream)
{
    (void)in_sizes; (void)n_in; (void)out_size; (void)ws_size;
    const float* pcd = (const float*)d_in[0];   // [8,4096,3] f32
    float* out = (float*)d_out;                 // [8,4096] f32 (trace, then curvature)
    u32* ctr = (u32*)d_ws;                      // 8 fan-in counters

    hipMemsetAsync(ctr, 0, BATCH * sizeof(u32), stream);
    dim3 grid(N_PTS / QPB, BATCH);              // 64 x 8 = 512 blocks
    fused_kernel<<<grid, NTHR, 0, stream>>>(pcd, out, ctr);
}